// Round 5
// baseline (1337.359 us; speedup 1.0000x reference)
//
#include <hip/hip_runtime.h>
#include <math.h>

#define BB 512
#define NN 16
#define CC 256
#define KK 8192
#define BNC (BB*NN*CC)

typedef unsigned short u16;
typedef __attribute__((ext_vector_type(8))) short bf16x8;
typedef __attribute__((ext_vector_type(4))) float f32x4;

__device__ __forceinline__ u16 f2bf(float x) {
    unsigned u = __float_as_uint(x);
    unsigned r = (u + 0x7fffu + ((u >> 16) & 1u)) >> 16;
    return (u16)r;
}

__device__ __forceinline__ void gl2lds16(const void* g, void* l) {
    __builtin_amdgcn_global_load_lds(
        (const __attribute__((address_space(1))) void*)g,
        (__attribute__((address_space(3))) void*)l,
        16, 0, 0);
}

// ---------------------------------------------------------------------------
__global__ void esq_kernel(const float* __restrict__ emb, float* __restrict__ e_sq) {
    int gid  = blockIdx.x * blockDim.x + threadIdx.x;
    int wave = gid >> 6;
    int lane = gid & 63;
    const float4 v = *(const float4*)(emb + (size_t)wave * CC + lane * 4);
    float s = v.x*v.x + v.y*v.y + v.z*v.z + v.w*v.w;
    #pragma unroll
    for (int m = 32; m >= 1; m >>= 1) s += __shfl_xor(s, m, 64);
    if (lane == 0) e_sq[wave] = s;
}

__global__ void cvt_emb_kernel(const float* __restrict__ emb, u16* __restrict__ out) {
    int gid = blockIdx.x * blockDim.x + threadIdx.x;
    float4 v = ((const float4*)emb)[gid];
    ushort4 o;
    o.x = f2bf(v.x); o.y = f2bf(v.y); o.z = f2bf(v.z); o.w = f2bf(v.w);
    ((ushort4*)out)[gid] = o;
}

// initial pool for pn=1
__global__ void init_pool_kernel(const float* __restrict__ f,
                                 u16* __restrict__ rest_bf) {
    int b = blockIdx.x;
    int c = threadIdx.x;
    const float* base = f + (size_t)b * NN * CC + c;
    float acc = 0.f;
    #pragma unroll
    for (int n = 0; n < NN; ++n) acc += base[(size_t)n * CC];
    rest_bf[(size_t)b * CC + c] = f2bf(acc * (1.0f / 16.0f));
}

// ---------------------------------------------------------------------------
__device__ __forceinline__ unsigned long long shfl_xor_u64(unsigned long long v, int m) {
    unsigned lo = (unsigned)v, hi = (unsigned)(v >> 32);
    lo = __shfl_xor(lo, m, 64);
    hi = __shfl_xor(hi, m, 64);
    return ((unsigned long long)hi << 32) | lo;
}

// MFMA distance+argmin, barrier-free K-loop, register-double-buffered B.
// A: 64 rows x 256 K resident in LDS (XOR-swizzled, conflict-free), staged once.
// B: direct global->VGPR bf16x8 loads (lanes l,l+16,l+32,l+48 share one 64B
// line => fully coalesced), prefetched one kc ahead; compiler emits
// fine-grained vmcnt(N) — the AITER-style MFMA<->load interleave.
// Per-row argmin in registers across all codes; one atomicMin per row at end.
__global__ __launch_bounds__(256, 2) void dist_mfma_kernel(
        const u16* __restrict__ A, const u16* __restrict__ Bm,
        const float* __restrict__ e_sq,
        unsigned long long* __restrict__ packed, int cpb) {
    __shared__ __align__(16) u16 sA[16384];   // 32 KB
    const int tid = threadIdx.x;
    const int w = tid >> 6, l = tid & 63;
    const int r0 = blockIdx.x * 64;
    const int c0 = blockIdx.y * cpb;
    const int ncb = cpb >> 8;
    const int arow = l & 15;
    const int aq   = l >> 4;

    // ---- stage A once: slot s = row*32 + (g ^ (row&31)), 16B granules ----
    {
        const int phys = tid & 31;
        #pragma unroll
        for (int i = 0; i < 8; ++i) {
            int s = tid + 256 * i;
            int row = s >> 5;
            int g = phys ^ (row & 31);
            gl2lds16(A + (((size_t)(r0 + row)) << 8) + g * 8,
                     (char*)sA + (size_t)(w * 64 + 256 * i) * 16);
        }
    }

    // B pointer: code = c0 + w*64 + t*16 + arow, k-offset = aq*8 (u16)
    const u16* bp = Bm + (((size_t)(c0 + w * 64 + arow)) << 8) + (aq << 3);
    const float* ep = e_sq + c0 + w * 64 + arow;

    bf16x8 bcur[4], bnxt[4];
    #pragma unroll
    for (int t = 0; t < 4; ++t)
        bcur[t] = *(const bf16x8*)(bp + t * 4096);

    __syncthreads();   // A visible; only barrier in the kernel

    float bestd[16];
    int   bestk[16];
    #pragma unroll
    for (int t = 0; t < 16; ++t) { bestd[t] = 1e30f; bestk[t] = 0; }

    for (int cb = 0; cb < ncb; ++cb) {
        // e_sq for this code group, issued early (used only at fold)
        float esq[4];
        #pragma unroll
        for (int j = 0; j < 4; ++j) esq[j] = ep[cb * 256 + j * 16];

        f32x4 acc[4][4];
        const f32x4 z = {0.f, 0.f, 0.f, 0.f};
        #pragma unroll
        for (int i = 0; i < 4; ++i)
            #pragma unroll
            for (int j = 0; j < 4; ++j) acc[i][j] = z;

        const bool lastcb = (cb == ncb - 1);
        #pragma unroll
        for (int kc = 0; kc < 8; ++kc) {
            // prefetch next kc (or next cb's kc=0); dummy re-read at very end
            size_t noff = (kc < 7) ? (size_t)((kc + 1) * 32)
                                   : (lastcb ? (size_t)(kc * 32) : (size_t)65536);
            #pragma unroll
            for (int t = 0; t < 4; ++t)
                bnxt[t] = *(const bf16x8*)(bp + noff + t * 4096);

            bf16x8 a[4];
            #pragma unroll
            for (int t = 0; t < 4; ++t) {
                int row = t * 16 + arow;
                a[t] = *(const bf16x8*)(sA + row * 256 + (((kc * 4 + aq) ^ (row & 31)) << 3));
            }
            #pragma unroll
            for (int i = 0; i < 4; ++i)
                #pragma unroll
                for (int j = 0; j < 4; ++j)
                    acc[i][j] = __builtin_amdgcn_mfma_f32_16x16x32_bf16(
                                    a[i], bcur[j], acc[i][j], 0, 0, 0);
            #pragma unroll
            for (int t = 0; t < 4; ++t) bcur[t] = bnxt[t];
        }
        bp += 65536;

        // fold this 256-code group into running per-lane argmin
        #pragma unroll
        for (int i = 0; i < 4; ++i)
            #pragma unroll
            for (int r = 0; r < 4; ++r) {
                const int slot = i * 4 + r;
                #pragma unroll
                for (int j = 0; j < 4; ++j) {
                    float d = fmaf(-2.0f, acc[i][j][r], esq[j]);
                    int k = c0 + cb * 256 + w * 64 + j * 16 + arow;
                    if (d < bestd[slot]) { bestd[slot] = d; bestk[slot] = k; }
                }
            }
    }

    // cross-lane merge (16 lanes sharing aq hold the same rows) + global merge
    #pragma unroll
    for (int t = 0; t < 16; ++t) {
        unsigned u = __float_as_uint(bestd[t]);
        u = (u & 0x80000000u) ? ~u : (u | 0x80000000u);
        unsigned long long p = ((unsigned long long)u << 32) | (unsigned)bestk[t];
        #pragma unroll
        for (int m = 1; m < 16; m <<= 1) {
            unsigned long long o = shfl_xor_u64(p, m);
            if (o < p) p = o;
        }
        if (arow == 0)
            atomicMin(&packed[r0 + (t >> 2) * 16 + aq * 4 + (t & 3)], p);
    }
}

// ---------------------------------------------------------------------------
// Fused: gather + upsample + f_hat/f_rest update + qlat partial + pool for pn+1.
__global__ void update_pool_kernel(const float* __restrict__ f,
                                   const float* __restrict__ emb,
                                   const unsigned long long* __restrict__ packed,
                                   float* __restrict__ f_rest,
                                   float* __restrict__ f_hat,
                                   float* __restrict__ slots,
                                   u16* __restrict__ rest_bf, int pn) {
    int b = blockIdx.x;
    int c = threadIdx.x;
    __shared__ int sk[NN];
    __shared__ float red[4];
    if (threadIdx.x < pn)
        sk[threadIdx.x] = (int)(unsigned)(packed[b * pn + threadIdx.x] & 0xffffffffull);
    __syncthreads();

    float fr[NN];
    float acc_sq = 0.f;
    #pragma unroll
    for (int n = 0; n < NN; ++n) {
        double pos = (n + 0.5) * ((double)pn / 16.0) - 0.5;
        if (pos < 0.0) pos = 0.0;
        int i0 = (int)floor(pos);
        if (i0 > pn - 1) i0 = pn - 1;
        int i1 = i0 + 1;
        if (i1 > pn - 1) i1 = pn - 1;
        double frac = pos - (double)i0;
        float w1 = (float)frac;
        float w0 = (float)(1.0 - frac);
        float h = w0 * emb[(size_t)sk[i0] * CC + c] + w1 * emb[(size_t)sk[i1] * CC + c];
        size_t off = ((size_t)b * NN + n) * CC + c;
        float fh = f_hat[off] + h;
        f_hat[off] = fh;
        float fre = f_rest[off] - h;
        f_rest[off] = fre;
        fr[n] = fre;
        float diff = fh - f[off];
        acc_sq += diff * diff;
    }

    int wv = threadIdx.x >> 6, ln = threadIdx.x & 63;
    #pragma unroll
    for (int m = 32; m >= 1; m >>= 1) acc_sq += __shfl_xor(acc_sq, m, 64);
    if (ln == 0) red[wv] = acc_sq;

    int pn2 = pn + 1;
    if (pn < NN) {
        for (int p = 0; p < pn2; ++p) {
            int s = (p * NN) / pn2;
            int e = ((p + 1) * NN + pn2 - 1) / pn2;
            float v = 0.f;
            for (int n = s; n < e; ++n) v += fr[n];
            v *= 1.0f / (float)(e - s);
            rest_bf[((size_t)(b * pn2 + p)) * CC + c] = f2bf(v);
        }
    }
    __syncthreads();
    if (threadIdx.x == 0)
        atomicAdd(&slots[b & 255], (red[0] + red[1]) + (red[2] + red[3]));
}

// ---------------------------------------------------------------------------
__global__ void final_kernel(const float* __restrict__ slots, float* __restrict__ out_scalars) {
    float v = slots[threadIdx.x];
    #pragma unroll
    for (int m = 32; m >= 1; m >>= 1) v += __shfl_xor(v, m, 64);
    __shared__ float red[4];
    int wv = threadIdx.x >> 6, ln = threadIdx.x & 63;
    if (ln == 0) red[wv] = v;
    __syncthreads();
    if (threadIdx.x == 0) {
        float S = (red[0] + red[1]) + (red[2] + red[3]);
        float qlat = S / (float)BNC / (float)NN;
        out_scalars[0] = 0.25f * qlat;   // commit
        out_scalars[1] = qlat;           // qlat
    }
}

// ---------------------------------------------------------------------------
extern "C" void kernel_launch(void* const* d_in, const int* in_sizes, int n_in,
                              void* d_out, int out_size, void* d_ws, size_t ws_size,
                              hipStream_t stream) {
    (void)in_sizes; (void)n_in; (void)out_size; (void)ws_size;
    const float* f   = (const float*)d_in[0];   // [B, N, C]
    const float* emb = (const float*)d_in[1];   // [K, C]
    float* out = (float*)d_out;                 // f_hat [B*N*C] + 2 scalars

    float* ws      = (float*)d_ws;
    float* f_rest  = ws;                                   // BNC floats
    float* r2_pad  = f_rest + BNC;                         // 8192 (layout keep)
    float* e_sq    = r2_pad + BB * NN;                     // K
    float* slots   = e_sq + KK;                            // 256
    unsigned long long* packed_all = (unsigned long long*)(slots + 256);  // 512*136
    u16* rest_bf = (u16*)(packed_all + (size_t)BB * 136);  // 8192*256 bf16
    u16* emb_bf  = rest_bf + (size_t)BB * NN * CC;         // K*C bf16

    float* f_hat = out;  // accumulate output in place

    hipMemsetAsync(out, 0, (size_t)BNC * sizeof(float), stream);
    hipMemcpyAsync(f_rest, f, (size_t)BNC * sizeof(float), hipMemcpyDeviceToDevice, stream);
    hipMemsetAsync(slots, 0, 256 * sizeof(float), stream);
    hipMemsetAsync(packed_all, 0xFF, (size_t)BB * 136 * sizeof(unsigned long long), stream);
    esq_kernel<<<KK / 4, 256, 0, stream>>>(emb, e_sq);
    cvt_emb_kernel<<<KK * CC / 4 / 256, 256, 0, stream>>>(emb, emb_bf);
    init_pool_kernel<<<BB, 256, 0, stream>>>(f, rest_bf);

    // codebook splits per pn: keep grid >= ~256 blocks, cpb >= 256
    static const int splits_tab[17] = {0,32,32,16,16,8,8,8,8,4,4,4,4,4,4,4,4};

    for (int pn = 1; pn <= NN; ++pn) {
        unsigned long long* packed = packed_all + (size_t)BB * (pn * (pn - 1) / 2);
        int splits = splits_tab[pn];
        int cpb = KK / splits;
        dim3 grid(BB * pn / 64, splits);
        dist_mfma_kernel<<<grid, 256, 0, stream>>>(rest_bf, emb_bf, e_sq, packed, cpb);
        update_pool_kernel<<<BB, 256, 0, stream>>>(f, emb, packed, f_rest, f_hat,
                                                   slots, rest_bf, pn);
    }
    final_kernel<<<1, 256, 0, stream>>>(slots, out + BNC);
}

// Round 6
// 1240.461 us; speedup vs baseline: 1.0781x; 1.0781x over previous
//
#include <hip/hip_runtime.h>
#include <math.h>

#define BB 512
#define NN 16
#define CC 256
#define KK 8192
#define BNC (BB*NN*CC)
#define KE 272            // 256 + 16 ext cols (col 256: A=1.0, B=-e_sq/2)

typedef unsigned short u16;
typedef __attribute__((ext_vector_type(8))) short bf16x8;
typedef __attribute__((ext_vector_type(16))) float f32x16;

__device__ __forceinline__ u16 f2bf(float x) {
    unsigned u = __float_as_uint(x);
    unsigned r = (u + 0x7fffu + ((u >> 16) & 1u)) >> 16;
    return (u16)r;
}

__device__ __forceinline__ void gl2lds16(const void* g, void* l) {
    __builtin_amdgcn_global_load_lds(
        (const __attribute__((address_space(1))) void*)g,
        (__attribute__((address_space(3))) void*)l,
        16, 0, 0);
}

// ---------------------------------------------------------------------------
// emb fp32 -> bf16 ext row: [256 bf16 vals][-e_sq/2][0 x15]. One wave per code.
__global__ void cvt_emb_kernel(const float* __restrict__ emb, u16* __restrict__ out) {
    int gid  = blockIdx.x * blockDim.x + threadIdx.x;
    int code = gid >> 6, l = gid & 63;
    const float4 v = *(const float4*)(emb + (size_t)code * CC + l * 4);
    ushort4 o;
    o.x = f2bf(v.x); o.y = f2bf(v.y); o.z = f2bf(v.z); o.w = f2bf(v.w);
    *(ushort4*)(out + (size_t)code * KE + l * 4) = o;
    float s = v.x*v.x + v.y*v.y + v.z*v.z + v.w*v.w;
    #pragma unroll
    for (int m = 32; m >= 1; m >>= 1) s += __shfl_xor(s, m, 64);
    if (l < 4) {
        ushort4 e; e.x = (l == 0) ? f2bf(-0.5f * s) : 0; e.y = 0; e.z = 0; e.w = 0;
        *(ushort4*)(out + (size_t)code * KE + 256 + l * 4) = e;
    }
}

// initial pool for pn=1 (ext row format)
__global__ void init_pool_kernel(const float* __restrict__ f,
                                 u16* __restrict__ rest_bf) {
    int b = blockIdx.x;
    int c = threadIdx.x;
    const float* base = f + (size_t)b * NN * CC + c;
    float acc = 0.f;
    #pragma unroll
    for (int n = 0; n < NN; ++n) acc += base[(size_t)n * CC];
    rest_bf[(size_t)b * KE + c] = f2bf(acc * (1.0f / 16.0f));
    if (c < 16) rest_bf[(size_t)b * KE + 256 + c] = (c == 0) ? 0x3F80 : 0;
}

// ---------------------------------------------------------------------------
__device__ __forceinline__ unsigned long long shfl_xor_u64(unsigned long long v, int m) {
    unsigned lo = (unsigned)v, hi = (unsigned)(v >> 32);
    lo = __shfl_xor(lo, m, 64);
    hi = __shfl_xor(hi, m, 64);
    return ((unsigned long long)hi << 32) | lo;
}

// MFMA distance+argmin. A (64 rows x 272) LDS-resident, stride 280 u16
// (bank-quad spread). B: 3-slot wave-private LDS ring of 2KB chunks
// (64 codes x 16 k), staged 2 ahead via global_load_lds, waited with
// vmcnt(4) — no barriers, no global loads in the K-loop (e_sq folded into
// the ext column). 32x32x16 bf16 MFMA, wave tile 64x64, acc = dot - e_sq/2;
// argmin key = -2*acc == e_sq - 2*dot. Per-lane running argmax(acc), merged
// via shfl + one atomicMin per row.
__global__ __launch_bounds__(256, 2) void dist_mfma_kernel(
        const u16* __restrict__ A, const u16* __restrict__ Bm,
        unsigned long long* __restrict__ packed, int cpb) {
    __shared__ __align__(16) u16 sA[64 * 280];      // 35840 B
    __shared__ __align__(16) u16 sB[4 * 3 * 1024];  // 24576 B
    const int tid = threadIdx.x;
    const int w = tid >> 6, l = tid & 63;
    const int half = l >> 5, l31 = l & 31;
    const int r0 = blockIdx.x * 64;
    const int c0 = blockIdx.y * cpb;
    const int ncb = cpb >> 8;

    // ---- stage A once: LDS slot s = r*35 + g (g<34 real, g=34 pad) ----
    #pragma unroll
    for (int rnd = 0; rnd < 9; ++rnd) {
        int s = rnd * 256 + tid;
        if (s < 64 * 35) {
            int r = s / 35, g = s - r * 35;
            if (g < 34)
                gl2lds16(A + (size_t)(r0 + r) * KE + g * 8,
                         (char*)sA + (size_t)(rnd * 256 + w * 64) * 16);
        }
    }

    // ---- B chunk staging: slot layout [kh][code]; 2 ops of 1KB each ----
    #define STAGE_B(cb_, kc_, sl_)                                             \
        {                                                                      \
            const u16* src_ = Bm + (size_t)(c0 + (cb_) * 256 + w * 64 + l) * KE \
                              + (kc_) * 16;                                    \
            char* dst_ = (char*)sB + (size_t)(w * 3 + (sl_)) * 2048;           \
            gl2lds16(src_, dst_);                                              \
            gl2lds16(src_ + 8, dst_ + 1024);                                   \
        }

    STAGE_B(0, 0, 0);
    STAGE_B(0, 1, 1);
    __syncthreads();   // A + chunks 0,1 visible; only barrier in the kernel

    float bestacc[32];
    int   bestk[32];
    #pragma unroll
    for (int t = 0; t < 32; ++t) { bestacc[t] = -1e30f; bestk[t] = 0; }

    int sc = 0, ss = 2;   // ring slot of compute chunk / staging target
    for (int cb = 0; cb < ncb; ++cb) {
        f32x16 acc[2][2];
        #pragma unroll
        for (int i = 0; i < 2; ++i)
            #pragma unroll
            for (int j = 0; j < 2; ++j)
                #pragma unroll
                for (int r = 0; r < 16; ++r) acc[i][j][r] = 0.f;

        #pragma unroll
        for (int kc = 0; kc < 17; ++kc) {
            // stage chunk (cb,kc)+2 (clamped dummy at the tail)
            int kc2 = kc + 2, cb2 = cb;
            if (kc2 >= 17) { kc2 -= 17; cb2 += 1; }
            if (cb2 >= ncb) { cb2 = ncb - 1; kc2 = 16; }
            STAGE_B(cb2, kc2, ss);
            __builtin_amdgcn_s_waitcnt(0x0F74);   // vmcnt(4): chunk (cb,kc) ready

            bf16x8 a[2], b[2];
            const u16* wb = sB + (size_t)(w * 3 + sc) * 1024;
            #pragma unroll
            for (int t = 0; t < 2; ++t) {
                int row = t * 32 + l31;
                a[t] = *(const bf16x8*)(sA + row * 35 * 8 + (kc * 2 + half) * 8);
                b[t] = *(const bf16x8*)(wb + (half * 64 + t * 32 + l31) * 8);
            }
            #pragma unroll
            for (int i = 0; i < 2; ++i)
                #pragma unroll
                for (int j = 0; j < 2; ++j)
                    acc[i][j] = __builtin_amdgcn_mfma_f32_32x32x16_bf16(
                                    a[i], b[j], acc[i][j], 0, 0, 0);
            sc = (sc == 2) ? 0 : sc + 1;
            ss = (ss == 2) ? 0 : ss + 1;
        }

        // fold: argmax acc over codes (== argmin e_sq - 2dot); strict > keeps
        // the smallest k (j,cb ascending)
        #pragma unroll
        for (int i = 0; i < 2; ++i)
            #pragma unroll
            for (int r = 0; r < 16; ++r) {
                const int slot = i * 16 + r;
                #pragma unroll
                for (int j = 0; j < 2; ++j) {
                    float v = acc[i][j][r];
                    if (v > bestacc[slot]) {
                        bestacc[slot] = v;
                        bestk[slot] = c0 + cb * 256 + w * 64 + j * 32 + l31;
                    }
                }
            }
    }

    // merge across the 32 lanes of each half (they share rows), then atomicMin
    #pragma unroll
    for (int i = 0; i < 2; ++i)
        #pragma unroll
        for (int r = 0; r < 16; ++r) {
            const int slot = i * 16 + r;
            float d = -2.0f * bestacc[slot];
            unsigned u = __float_as_uint(d);
            u = (u & 0x80000000u) ? ~u : (u | 0x80000000u);
            unsigned long long p = ((unsigned long long)u << 32) | (unsigned)bestk[slot];
            #pragma unroll
            for (int m = 1; m < 32; m <<= 1) {
                unsigned long long o = shfl_xor_u64(p, m);
                if (o < p) p = o;
            }
            if (l31 == 0)
                atomicMin(&packed[r0 + i * 32 + (r & 3) + 8 * (r >> 2) + 4 * half], p);
        }
    #undef STAGE_B
}

// ---------------------------------------------------------------------------
// Fused: gather + upsample + f_hat/f_rest update + qlat partial + pool for pn+1.
__global__ void update_pool_kernel(const float* __restrict__ f,
                                   const float* __restrict__ emb,
                                   const unsigned long long* __restrict__ packed,
                                   float* __restrict__ f_rest,
                                   float* __restrict__ f_hat,
                                   float* __restrict__ slots,
                                   u16* __restrict__ rest_bf, int pn) {
    int b = blockIdx.x;
    int c = threadIdx.x;
    __shared__ int sk[NN];
    __shared__ float red[4];
    if (threadIdx.x < pn)
        sk[threadIdx.x] = (int)(unsigned)(packed[b * pn + threadIdx.x] & 0xffffffffull);
    __syncthreads();

    float fr[NN];
    float acc_sq = 0.f;
    #pragma unroll
    for (int n = 0; n < NN; ++n) {
        double pos = (n + 0.5) * ((double)pn / 16.0) - 0.5;
        if (pos < 0.0) pos = 0.0;
        int i0 = (int)floor(pos);
        if (i0 > pn - 1) i0 = pn - 1;
        int i1 = i0 + 1;
        if (i1 > pn - 1) i1 = pn - 1;
        double frac = pos - (double)i0;
        float w1 = (float)frac;
        float w0 = (float)(1.0 - frac);
        float h = w0 * emb[(size_t)sk[i0] * CC + c] + w1 * emb[(size_t)sk[i1] * CC + c];
        size_t off = ((size_t)b * NN + n) * CC + c;
        float fh = f_hat[off] + h;
        f_hat[off] = fh;
        float fre = f_rest[off] - h;
        f_rest[off] = fre;
        fr[n] = fre;
        float diff = fh - f[off];
        acc_sq += diff * diff;
    }

    int wv = threadIdx.x >> 6, ln = threadIdx.x & 63;
    #pragma unroll
    for (int m = 32; m >= 1; m >>= 1) acc_sq += __shfl_xor(acc_sq, m, 64);
    if (ln == 0) red[wv] = acc_sq;

    int pn2 = pn + 1;
    if (pn < NN) {
        for (int p = 0; p < pn2; ++p) {
            int s = (p * NN) / pn2;
            int e = ((p + 1) * NN + pn2 - 1) / pn2;
            float v = 0.f;
            for (int n = s; n < e; ++n) v += fr[n];
            v *= 1.0f / (float)(e - s);
            size_t row = (size_t)(b * pn2 + p);
            rest_bf[row * KE + c] = f2bf(v);
            if (c < 16) rest_bf[row * KE + 256 + c] = (c == 0) ? 0x3F80 : 0;
        }
    }
    __syncthreads();
    if (threadIdx.x == 0)
        atomicAdd(&slots[b & 255], (red[0] + red[1]) + (red[2] + red[3]));
}

// ---------------------------------------------------------------------------
__global__ void final_kernel(const float* __restrict__ slots, float* __restrict__ out_scalars) {
    float v = slots[threadIdx.x];
    #pragma unroll
    for (int m = 32; m >= 1; m >>= 1) v += __shfl_xor(v, m, 64);
    __shared__ float red[4];
    int wv = threadIdx.x >> 6, ln = threadIdx.x & 63;
    if (ln == 0) red[wv] = v;
    __syncthreads();
    if (threadIdx.x == 0) {
        float S = (red[0] + red[1]) + (red[2] + red[3]);
        float qlat = S / (float)BNC / (float)NN;
        out_scalars[0] = 0.25f * qlat;   // commit
        out_scalars[1] = qlat;           // qlat
    }
}

// ---------------------------------------------------------------------------
extern "C" void kernel_launch(void* const* d_in, const int* in_sizes, int n_in,
                              void* d_out, int out_size, void* d_ws, size_t ws_size,
                              hipStream_t stream) {
    (void)in_sizes; (void)n_in; (void)out_size; (void)ws_size;
    const float* f   = (const float*)d_in[0];   // [B, N, C]
    const float* emb = (const float*)d_in[1];   // [K, C]
    float* out = (float*)d_out;                 // f_hat [B*N*C] + 2 scalars

    float* ws      = (float*)d_ws;
    float* f_rest  = ws;                                   // BNC floats
    float* slots   = f_rest + BNC;                         // 256
    unsigned long long* packed_all = (unsigned long long*)(slots + 256);  // 512*136
    u16* rest_bf = (u16*)(packed_all + (size_t)BB * 136);  // 8192*272 bf16 ext
    u16* emb_bf  = rest_bf + (size_t)BB * NN * KE;         // 8192*272 bf16 ext

    float* f_hat = out;  // accumulate output in place

    hipMemsetAsync(out, 0, (size_t)BNC * sizeof(float), stream);
    hipMemcpyAsync(f_rest, f, (size_t)BNC * sizeof(float), hipMemcpyDeviceToDevice, stream);
    hipMemsetAsync(slots, 0, 256 * sizeof(float), stream);
    hipMemsetAsync(packed_all, 0xFF, (size_t)BB * 136 * sizeof(unsigned long long), stream);
    cvt_emb_kernel<<<KK / 4, 256, 0, stream>>>(emb, emb_bf);
    init_pool_kernel<<<BB, 256, 0, stream>>>(f, rest_bf);

    // codebook splits per pn: keep grid >= ~256 blocks, cpb >= 256
    static const int splits_tab[17] = {0,32,32,16,16,8,8,8,8,4,4,4,4,4,4,4,4};

    for (int pn = 1; pn <= NN; ++pn) {
        unsigned long long* packed = packed_all + (size_t)BB * (pn * (pn - 1) / 2);
        int splits = splits_tab[pn];
        int cpb = KK / splits;
        dim3 grid(BB * pn / 64, splits);
        dist_mfma_kernel<<<grid, 256, 0, stream>>>(rest_bf, emb_bf, packed, cpb);
        update_pool_kernel<<<BB, 256, 0, stream>>>(f, emb, packed, f_rest, f_hat,
                                                   slots, rest_bf, pn);
    }
    final_kernel<<<1, 256, 0, stream>>>(slots, out + BNC);
}

// Round 7
// 957.213 us; speedup vs baseline: 1.3971x; 1.2959x over previous
//
#include <hip/hip_runtime.h>
#include <math.h>

#define BB 512
#define NN 16
#define CC 256
#define KK 8192
#define BNC (BB*NN*CC)

typedef unsigned short u16;
typedef unsigned char u8;
typedef unsigned long long u64;
typedef __attribute__((ext_vector_type(8))) int i32x8;
typedef __attribute__((ext_vector_type(4))) float f32x4;

#define SCALE_A 0x7D7D7D7D   // e8m0 125 -> 2^-2  (A stored x4)
#define SCALE_B 0x73737373   // e8m0 115 -> 2^-12 (B stored x4096)

__device__ __forceinline__ void gl2lds16(const void* g, void* l) {
    __builtin_amdgcn_global_load_lds(
        (const __attribute__((address_space(1))) void*)g,
        (__attribute__((address_space(3))) void*)l, 16, 0, 0);
}
__device__ __forceinline__ void gl2lds4(const void* g, void* l) {
    __builtin_amdgcn_global_load_lds(
        (const __attribute__((address_space(1))) void*)g,
        (__attribute__((address_space(3))) void*)l, 4, 0, 0);
}
__device__ __forceinline__ u8 f2fp8(float x) {
    int r = __builtin_amdgcn_cvt_pk_fp8_f32(x, x, 0, false);
    return (u8)(r & 0xFF);
}
__device__ __forceinline__ u64 shfl_xor_u64(u64 v, int m) {
    unsigned lo = (unsigned)v, hi = (unsigned)(v >> 32);
    lo = __shfl_xor(lo, m, 64);
    hi = __shfl_xor(hi, m, 64);
    return ((u64)hi << 32) | lo;
}

// ---------------------------------------------------------------------------
// emb fp32 -> fp8 e4m3 (stored x4096); e_sq from the QUANTIZED codebook.
__global__ void cvt_emb_kernel(const float* __restrict__ emb,
                               u8* __restrict__ out, float* __restrict__ e_sq) {
    int gid = blockIdx.x * blockDim.x + threadIdx.x;
    int code = gid >> 6, l = gid & 63;
    float4 v = *(const float4*)(emb + (size_t)code * CC + l * 4);
    int p = __builtin_amdgcn_cvt_pk_fp8_f32(v.x * 4096.f, v.y * 4096.f, 0, false);
    p = __builtin_amdgcn_cvt_pk_fp8_f32(v.z * 4096.f, v.w * 4096.f, p, true);
    *(int*)(out + (size_t)code * CC + l * 4) = p;
    float dx = __builtin_amdgcn_cvt_f32_fp8(p, 0);
    float dy = __builtin_amdgcn_cvt_f32_fp8(p, 1);
    float dz = __builtin_amdgcn_cvt_f32_fp8(p, 2);
    float dw = __builtin_amdgcn_cvt_f32_fp8(p, 3);
    float s = dx*dx + dy*dy + dz*dz + dw*dw;
    #pragma unroll
    for (int m = 32; m >= 1; m >>= 1) s += __shfl_xor(s, m, 64);
    if (l == 0) e_sq[code] = s * 5.9604644775390625e-8f;   // 2^-24
}

// initial pool for pn=1: mean over 16 n, fp8 (x4)
__global__ void init_pool_kernel(const float* __restrict__ f,
                                 u8* __restrict__ rest8) {
    int b = blockIdx.x;
    int c = threadIdx.x;
    const float* base = f + (size_t)b * NN * CC + c;
    float acc = 0.f;
    #pragma unroll
    for (int n = 0; n < NN; ++n) acc += base[(size_t)n * CC];
    rest8[(size_t)b * CC + c] = f2fp8(acc * (4.0f / 16.0f));
}

// ---------------------------------------------------------------------------
// MX-fp8 distance+argmin. A: 64 rows x 256 fp8 in VGPRs (loaded once).
// B: ring-2 wave-private LDS chunks (64 codes x 128 k = 8 KB), staged at
// iter end into the just-consumed slot, uniform vmcnt(8), zero barriers.
// mfma_scale_f32_16x16x128_f8f6f4, wave tile 64 rows x 64 codes (4x4 of
// 16x16). d = e_sq - 2*dot via per-cb fold; index packed in low 7 mantissa
// bits; one atomicMin per row at the end.
__global__ __launch_bounds__(256, 2) void dist_mx_kernel(
        const u8* __restrict__ A, const u8* __restrict__ Bm,
        const float* __restrict__ e_sq,
        u64* __restrict__ packed, int cpb) {
    __shared__ __align__(16) u8 sB[4 * 2 * 8192];   // 64 KB
    __shared__ __align__(16) float sE[4 * 512];     // 8 KB (<= 8 cb x 64 codes)
    const int tid = threadIdx.x;
    const int w = tid >> 6, l = tid & 63;
    const int ccol = l & 15, quad = l >> 4;
    const int r0 = blockIdx.x * 64;
    const int c0 = blockIdx.y * cpb;
    const int ncb = cpb >> 8;
    const int sg = ((l & 7) - (l >> 3)) & 7;        // stage granule perm

    // ---- A fragments -> VGPRs (16 dwordx4 loads, quarter-wave 128B segs) ----
    i32x8 afr[4][2];
    #pragma unroll
    for (int t = 0; t < 4; ++t)
        #pragma unroll
        for (int ki = 0; ki < 2; ++ki) {
            const u8* ap = A + (size_t)(r0 + t * 16 + ccol) * CC + ki * 128 + quad * 32;
            int4 lo = *(const int4*)ap;
            int4 hi = *(const int4*)(ap + 16);
            i32x8 v;
            v[0]=lo.x; v[1]=lo.y; v[2]=lo.z; v[3]=lo.w;
            v[4]=hi.x; v[5]=hi.y; v[6]=hi.z; v[7]=hi.w;
            afr[t][ki] = v;
        }

    // ---- e_sq -> LDS (wave-private), width-4 async ----
    for (int cb = 0; cb < ncb; ++cb)
        gl2lds4(e_sq + c0 + cb * 256 + w * 64 + l,
                (char*)sE + w * 2048 + cb * 256);

    // ---- B chunk staging: slot(c,g) = 8c + ((g + (c&7)) & 7), 16B granules --
    #define STAGE(cb_, ki_)                                                     \
        {                                                                       \
            const u8* cbase = Bm + (size_t)(c0 + (cb_) * 256 + w * 64) * CC     \
                              + (ki_) * 128;                                    \
            char* dstb = (char*)sB + (size_t)(w * 2 + (ki_)) * 8192;            \
            _Pragma("unroll")                                                   \
            for (int o = 0; o < 8; ++o)                                         \
                gl2lds16(cbase + (size_t)(8 * o + (l >> 3)) * CC + sg * 16,     \
                         dstb + o * 1024);                                      \
        }

    STAGE(0, 0);
    STAGE(0, 1);

    const unsigned smask = 0xFFFFFF80u;
    float best[16];
    #pragma unroll
    for (int t = 0; t < 16; ++t) best[t] = 1e30f;

    f32x4 acc[4][4];
    const int nci = 2 * ncb;
    for (int ci = 0; ci < nci; ++ci) {
        const int cb = ci >> 1, ki = ci & 1;
        __builtin_amdgcn_s_waitcnt(0x0F78);   // vmcnt(8): chunk ci ready

        // b-frags from slot ki (conflict-free by slot perm)
        const u8* wb = sB + (size_t)(w * 2 + ki) * 8192;
        i32x8 bfr[4];
        #pragma unroll
        for (int j = 0; j < 4; ++j) {
            int c = j * 16 + ccol;
            int s0 = c * 8 + ((quad * 2 + 0 + (c & 7)) & 7);
            int s1 = c * 8 + ((quad * 2 + 1 + (c & 7)) & 7);
            int4 lo = *(const int4*)(wb + s0 * 16);
            int4 hi = *(const int4*)(wb + s1 * 16);
            i32x8 v;
            v[0]=lo.x; v[1]=lo.y; v[2]=lo.z; v[3]=lo.w;
            v[4]=hi.x; v[5]=hi.y; v[6]=hi.z; v[7]=hi.w;
            bfr[j] = v;
        }

        if (ki == 0) {
            const f32x4 z = {0.f, 0.f, 0.f, 0.f};
            #pragma unroll
            for (int t = 0; t < 4; ++t)
                #pragma unroll
                for (int j = 0; j < 4; ++j) acc[t][j] = z;
        }
        #pragma unroll
        for (int t = 0; t < 4; ++t)
            #pragma unroll
            for (int j = 0; j < 4; ++j)
                acc[t][j] = __builtin_amdgcn_mfma_scale_f32_16x16x128_f8f6f4(
                                afr[t][ki], bfr[j], acc[t][j],
                                0, 0, 0, SCALE_A, 0, SCALE_B);

        // stage chunk ci+2 into the just-consumed slot (clamped dummy at tail)
        int cn = cb + 1;
        if (cn >= ncb) cn = ncb - 1;
        if (ki == 0) { STAGE(cn, 0); } else { STAGE(cn, 1); }

        if (ki == 1) {
            // fold this 64-code group: d = e_sq - 2*dot, idx in low mantissa
            float ej[4];
            #pragma unroll
            for (int j = 0; j < 4; ++j)
                ej[j] = *(const float*)((char*)sE + w * 2048 + cb * 256
                                        + (j * 16 + ccol) * 4);
            #pragma unroll
            for (int t = 0; t < 4; ++t)
                #pragma unroll
                for (int r = 0; r < 4; ++r) {
                    const int slot = t * 4 + r;
                    #pragma unroll
                    for (int j = 0; j < 4; ++j) {
                        float d = fmaf(-2.0f, acc[t][j][r], ej[j]);
                        unsigned u = (__float_as_uint(d) & smask)
                                     | (unsigned)((cb << 2) | j);
                        best[slot] = fminf(best[slot], __uint_as_float(u));
                    }
                }
        }
    }
    #undef STAGE

    // epilogue: reconstruct k, cross-lane merge (16 lanes of each quad share
    // rows), one atomicMin per row
    #pragma unroll
    for (int t = 0; t < 4; ++t)
        #pragma unroll
        for (int r = 0; r < 4; ++r) {
            unsigned u = __float_as_uint(best[t * 4 + r]);
            int idx = u & 0x7F;
            int k = c0 + (idx >> 2) * 256 + w * 64 + (idx & 3) * 16 + ccol;
            int sgn = ((int)u) >> 31;
            unsigned ordu = u ^ ((unsigned)sgn | 0x80000000u);
            u64 p = ((u64)ordu << 32) | (unsigned)k;
            #pragma unroll
            for (int m = 1; m < 16; m <<= 1) {
                u64 o = shfl_xor_u64(p, m);
                if (o < p) p = o;
            }
            if (ccol == 0)
                atomicMin(&packed[r0 + t * 16 + quad * 4 + r], p);
        }
}

// ---------------------------------------------------------------------------
// Slim update: gather (fp32 emb) + upsample + f_rest update + qlat partial +
// fp8 pool for pn+1. f_hat never materialized (== f - f_rest); written to out
// only at pn==16.
__global__ void update_pool_kernel(const float* __restrict__ f,
                                   const float* __restrict__ emb,
                                   const u64* __restrict__ packed,
                                   float* __restrict__ f_rest,
                                   float* __restrict__ out,
                                   float* __restrict__ slots,
                                   u8* __restrict__ rest8, int pn) {
    int b = blockIdx.x;
    int c = threadIdx.x;
    __shared__ int sk[NN];
    __shared__ float red[4];
    if (threadIdx.x < pn)
        sk[threadIdx.x] = (int)(unsigned)(packed[b * pn + threadIdx.x] & 0xffffffffull);
    __syncthreads();

    float fr[NN];
    float acc_sq = 0.f;
    #pragma unroll
    for (int n = 0; n < NN; ++n) {
        double pos = (n + 0.5) * ((double)pn / 16.0) - 0.5;
        if (pos < 0.0) pos = 0.0;
        int i0 = (int)floor(pos);
        if (i0 > pn - 1) i0 = pn - 1;
        int i1 = i0 + 1;
        if (i1 > pn - 1) i1 = pn - 1;
        double frac = pos - (double)i0;
        float w1 = (float)frac;
        float w0 = (float)(1.0 - frac);
        float h = w0 * emb[(size_t)sk[i0] * CC + c] + w1 * emb[(size_t)sk[i1] * CC + c];
        size_t off = ((size_t)b * NN + n) * CC + c;
        float fre = f_rest[off] - h;
        f_rest[off] = fre;
        fr[n] = fre;
        acc_sq += fre * fre;
        if (pn == NN) out[off] = f[off] - fre;
    }

    int wv = threadIdx.x >> 6, ln = threadIdx.x & 63;
    #pragma unroll
    for (int m = 32; m >= 1; m >>= 1) acc_sq += __shfl_xor(acc_sq, m, 64);
    if (ln == 0) red[wv] = acc_sq;

    int pn2 = pn + 1;
    if (pn < NN) {
        for (int p = 0; p < pn2; ++p) {
            int s = (p * NN) / pn2;
            int e = ((p + 1) * NN + pn2 - 1) / pn2;
            float v = 0.f;
            for (int n = s; n < e; ++n) v += fr[n];
            v *= 1.0f / (float)(e - s);
            rest8[((size_t)(b * pn2 + p)) * CC + c] = f2fp8(4.0f * v);
        }
    }
    __syncthreads();
    if (threadIdx.x == 0)
        atomicAdd(&slots[b & 255], (red[0] + red[1]) + (red[2] + red[3]));
}

// ---------------------------------------------------------------------------
__global__ void final_kernel(const float* __restrict__ slots, float* __restrict__ out_scalars) {
    float v = slots[threadIdx.x];
    #pragma unroll
    for (int m = 32; m >= 1; m >>= 1) v += __shfl_xor(v, m, 64);
    __shared__ float red[4];
    int wv = threadIdx.x >> 6, ln = threadIdx.x & 63;
    if (ln == 0) red[wv] = v;
    __syncthreads();
    if (threadIdx.x == 0) {
        float S = (red[0] + red[1]) + (red[2] + red[3]);
        float qlat = S / (float)BNC / (float)NN;
        out_scalars[0] = 0.25f * qlat;   // commit
        out_scalars[1] = qlat;           // qlat
    }
}

// ---------------------------------------------------------------------------
extern "C" void kernel_launch(void* const* d_in, const int* in_sizes, int n_in,
                              void* d_out, int out_size, void* d_ws, size_t ws_size,
                              hipStream_t stream) {
    (void)in_sizes; (void)n_in; (void)out_size; (void)ws_size;
    const float* f   = (const float*)d_in[0];   // [B, N, C]
    const float* emb = (const float*)d_in[1];   // [K, C]
    float* out = (float*)d_out;                 // f_hat [B*N*C] + 2 scalars

    float* ws      = (float*)d_ws;
    float* f_rest  = ws;                                   // BNC floats
    float* e_sq    = f_rest + BNC;                         // K
    float* slots   = e_sq + KK;                            // 256
    u64* packed_all = (u64*)(slots + 256);                 // 512*136
    u8* rest8 = (u8*)(packed_all + (size_t)BB * 136);      // 8192*256 fp8
    u8* emb8  = rest8 + (size_t)BB * NN * CC;              // 8192*256 fp8

    hipMemcpyAsync(f_rest, f, (size_t)BNC * sizeof(float), hipMemcpyDeviceToDevice, stream);
    hipMemsetAsync(slots, 0, 256 * sizeof(float), stream);
    hipMemsetAsync(packed_all, 0xFF, (size_t)BB * 136 * sizeof(u64), stream);
    cvt_emb_kernel<<<KK / 4, 256, 0, stream>>>(emb, emb8, e_sq);
    init_pool_kernel<<<BB, 256, 0, stream>>>(f, rest8);

    // codebook splits per pn: keep grid >= ~256 blocks, ncb <= 8
    static const int splits_tab[17] = {0,32,32,16,16,8,8,8,8,4,4,4,4,4,4,4,4};

    for (int pn = 1; pn <= NN; ++pn) {
        u64* packed = packed_all + (size_t)BB * (pn * (pn - 1) / 2);
        int splits = splits_tab[pn];
        int cpb = KK / splits;
        dim3 grid(BB * pn / 64, splits);
        dist_mx_kernel<<<grid, 256, 0, stream>>>(rest8, emb8, e_sq, packed, cpb);
        update_pool_kernel<<<BB, 256, 0, stream>>>(f, emb, packed, f_rest, out,
                                                   slots, rest8, pn);
    }
    final_kernel<<<1, 256, 0, stream>>>(slots, out + BNC);
}